// Round 3
// baseline (195.416 us; speedup 1.0000x reference)
//
#include <hip/hip_runtime.h>
#include <hip/hip_bf16.h>
#include <stdint.h>

#define B_   64
#define L_   4096
#define H_   128
#define T_   64
#define C_   (L_/T_)        // 64 chunks
#define BH_  (B_*H_)        // 8192
#define PADI 136            // bf16 row stride for inp tile

typedef __attribute__((ext_vector_type(8))) short short8;
typedef __attribute__((ext_vector_type(4))) float floatx4;

#define LOG2E 1.44269504088896340736f

__device__ __forceinline__ unsigned short f2bf(float f){
    unsigned int u = __float_as_uint(f);
    u += 0x7FFFu + ((u >> 16) & 1u);      // RNE
    return (unsigned short)(u >> 16);
}
__device__ __forceinline__ float bf2f(unsigned short s){
    return __uint_as_float(((unsigned int)s) << 16);
}

// K0: W^T bf16 prep (dense [n][k]); B-fragments are read per-lane from global.
__global__ void prep_w(const float* __restrict__ Wz, const float* __restrict__ Wh,
                       unsigned short* __restrict__ WzT, unsigned short* __restrict__ WhT){
    const float* W = blockIdx.x ? Wh : Wz;
    unsigned short* WT = blockIdx.x ? WhT : WzT;
    int tid = threadIdx.x;
    for (int it = 0; it < 64; ++it){
        int idx = it*256 + tid;           // idx = n*128 + k
        int n = idx >> 7, k = idx & 127;
        WT[idx] = f2bf(W[k*H_ + n]);
    }
}

// K2: compose per-chunk aggregates into carries (h entering each chunk)
__global__ void chunk_scan(const float* __restrict__ aggA, const float* __restrict__ aggB,
                           float* __restrict__ carry){
    int tid = blockIdx.x*256 + threadIdx.x;   // 8192 = B*H
    float c = 0.0f;
    #pragma unroll 8
    for (int ch = 0; ch < C_; ++ch){
        carry[ch*BH_ + tid] = c;
        c = fmaf(aggA[ch*BH_ + tid], c, aggB[ch*BH_ + tid]);
    }
}

// ab LDS/global layout: row col (0..127) of 256B; 16B chunk t4 stored at
// position t4 ^ (col&15) (bank-balanced for all access phases). Pair (a,b)
// for step t=t4*4+e at ushorts [chunk*8 + 2e, +1].

// K1: inp + 2 GEMMs (B-frags from global WT, L2-hot) + gates + local scan.
// WRITE_AB: dump the 32KB ab tile to global for the cheap final pass.
// FINAL (fallback path): carried scan + readout instead of aggregates.
template<bool WRITE_AB, bool FINAL>
__global__ __launch_bounds__(256, 4)
void gemm_gates(const float* __restrict__ x,
                const float* __restrict__ Wp, const float* __restrict__ bp,
                const float* __restrict__ bz, const float* __restrict__ bh,
                const float* __restrict__ Wg, const float* __restrict__ bg,
                const unsigned short* __restrict__ WzT,
                const unsigned short* __restrict__ WhT,
                float* __restrict__ aggA, float* __restrict__ aggB,
                const float* __restrict__ carry,
                unsigned short* __restrict__ ab_g,
                float* __restrict__ preds)
{
    __shared__ __align__(16) unsigned short s_ab[H_*H_];   // 32768 B (inp tile overlays)
    __shared__ float s_bz[H_], s_bh[H_], s_wg[H_];
    unsigned short* inp_lds = s_ab;                        // 64*136 = 8704 ushorts

    const int bid = blockIdx.x;
    const int bb  = bid / C_;
    const int cc  = bid % C_;
    const int t0g = cc * T_;
    const int tid = threadIdx.x;
    const int wv = tid >> 6, lane = tid & 63, quad = lane >> 4, l15 = lane & 15;

    if (tid < H_){ s_bz[tid] = bz[tid]; s_bh[tid] = bh[tid]; if (FINAL) s_wg[tid] = Wg[tid]; }

    // ---- inp = x @ Wp + bp -> bf16 LDS (A layout [t][k]) ----
    #pragma unroll
    for (int it = 0; it < 4; ++it){
        int idx = tid + it*256;
        int t = idx >> 4, h0 = (idx & 15) * 8;
        const float* xr = x + ((size_t)bb*L_ + t0g + t)*3;
        float x0 = xr[0], x1 = xr[1], x2 = xr[2];
        short8 pk;
        #pragma unroll
        for (int m = 0; m < 8; ++m){
            int hh = h0 + m;
            float v = bp[hh];
            v = fmaf(x0, Wp[hh],      v);
            v = fmaf(x1, Wp[H_+hh],   v);
            v = fmaf(x2, Wp[2*H_+hh], v);
            pk[m] = (short)f2bf(v);
        }
        *(short8*)&inp_lds[t*PADI + h0] = pk;
    }
    __syncthreads();

    const int ct0 = wv*2;

    // ---- GEMM1: Sz = inp @ Wz^T (B-frags straight from global, L2-hot) ----
    floatx4 accz[4][2];
    #pragma unroll
    for (int r = 0; r < 4; ++r)
        #pragma unroll
        for (int c = 0; c < 2; ++c) accz[r][c] = (floatx4){0.f,0.f,0.f,0.f};
    #pragma unroll
    for (int kk = 0; kk < 4; ++kk){
        short8 af[4], bfr[2];
        #pragma unroll
        for (int r = 0; r < 4; ++r)
            af[r] = *(const short8*)&inp_lds[(r*16 + l15)*PADI + kk*32 + quad*8];
        #pragma unroll
        for (int c = 0; c < 2; ++c)
            bfr[c] = *(const short8*)&WzT[((ct0+c)*16 + l15)*H_ + kk*32 + quad*8];
        #pragma unroll
        for (int r = 0; r < 4; ++r)
            #pragma unroll
            for (int c = 0; c < 2; ++c)
                accz[r][c] = __builtin_amdgcn_mfma_f32_16x16x32_bf16(af[r], bfr[c], accz[r][c], 0, 0, 0);
    }

    // a = 1 - sigmoid(sz); quantize to bf16 now (frees accz)
    unsigned int a2[4][2][2];
    #pragma unroll
    for (int r = 0; r < 4; ++r){
        #pragma unroll
        for (int c = 0; c < 2; ++c){
            int col = (ct0+c)*16 + l15;
            float vbz = s_bz[col];
            unsigned short q[4];
            #pragma unroll
            for (int e = 0; e < 4; ++e){
                float szb = accz[r][c][e] + vbz;
                float a = __builtin_amdgcn_rcpf(1.0f + __builtin_amdgcn_exp2f(szb * LOG2E));
                q[e] = f2bf(a);
            }
            a2[r][c][0] = (unsigned int)q[0] | ((unsigned int)q[1] << 16);
            a2[r][c][1] = (unsigned int)q[2] | ((unsigned int)q[3] << 16);
        }
    }

    // ---- GEMM2: Sh = inp @ Wh^T ----
    floatx4 acch[4][2];
    #pragma unroll
    for (int r = 0; r < 4; ++r)
        #pragma unroll
        for (int c = 0; c < 2; ++c) acch[r][c] = (floatx4){0.f,0.f,0.f,0.f};
    #pragma unroll
    for (int kk = 0; kk < 4; ++kk){
        short8 af[4], bfr[2];
        #pragma unroll
        for (int r = 0; r < 4; ++r)
            af[r] = *(const short8*)&inp_lds[(r*16 + l15)*PADI + kk*32 + quad*8];
        #pragma unroll
        for (int c = 0; c < 2; ++c)
            bfr[c] = *(const short8*)&WhT[((ct0+c)*16 + l15)*H_ + kk*32 + quad*8];
        #pragma unroll
        for (int r = 0; r < 4; ++r)
            #pragma unroll
            for (int c = 0; c < 2; ++c)
                acch[r][c] = __builtin_amdgcn_mfma_f32_16x16x32_bf16(af[r], bfr[c], acch[r][c], 0, 0, 0);
    }
    __syncthreads();   // inp reads done before ab overlay

    // ---- epilogue: b = (1-a)*tanh(sh); write swizzled (a,b) b128 chunks ----
    // C/D layout: col = lane&15 (+16*coltile), t-row = r*16 + quad*4 + e
    #pragma unroll
    for (int r = 0; r < 4; ++r){
        #pragma unroll
        for (int c = 0; c < 2; ++c){
            int col = (ct0+c)*16 + l15;
            float vbh = s_bh[col];
            short8 pk;
            #pragma unroll
            for (int e = 0; e < 4; ++e){
                unsigned short abf = (unsigned short)(a2[r][c][e>>1] >> ((e & 1)*16));
                float a = bf2f(abf);
                float z = 1.0f - a;
                float shb = acch[r][c][e] + vbh;
                float e2 = __builtin_amdgcn_exp2f(2.0f*LOG2E*fabsf(shb));
                float tt = 1.0f - 2.0f*__builtin_amdgcn_rcpf(e2 + 1.0f);
                float bt = z * copysignf(tt, shb);
                pk[2*e]   = (short)abf;
                pk[2*e+1] = (short)f2bf(bt);
            }
            int ch = (r*4 + quad) ^ l15;          // swizzled 16B chunk position
            *(short8*)&s_ab[col*H_ + ch*8] = pk;
        }
    }
    __syncthreads();

    if (WRITE_AB){
        unsigned short* dst = ab_g + (size_t)bid * (H_*H_);
        #pragma unroll
        for (int i = 0; i < 8; ++i){
            int idx = tid + i*256;
            *(short8*)&dst[idx*8] = *(const short8*)&s_ab[idx*8];
        }
    }

    if (!FINAL){
        if (tid < H_){
            float A = 1.0f, h = 0.0f;
            #pragma unroll
            for (int t4 = 0; t4 < 16; ++t4){
                short8 pr = *(const short8*)&s_ab[tid*H_ + ((t4 ^ (tid & 15)) << 3)];
                #pragma unroll
                for (int e = 0; e < 4; ++e){
                    float aa = bf2f((unsigned short)pr[2*e]);
                    float bv = bf2f((unsigned short)pr[2*e+1]);
                    A *= aa;
                    h = fmaf(aa, h, bv);
                }
            }
            aggA[cc*BH_ + bb*H_ + tid] = A;
            aggB[cc*BH_ + bb*H_ + tid] = h;
        }
    } else {
        if (tid < H_){
            float h = carry[cc*BH_ + bb*H_ + tid];
            float wgv = s_wg[tid];
            #pragma unroll
            for (int t4 = 0; t4 < 16; ++t4){
                int base = tid*H_ + ((t4 ^ (tid & 15)) << 3);
                short8 pr = *(const short8*)&s_ab[base];
                #pragma unroll
                for (int e = 0; e < 4; ++e){
                    float aa = bf2f((unsigned short)pr[2*e]);
                    float bv = bf2f((unsigned short)pr[2*e+1]);
                    s_ab[base + 2*e] = f2bf(h * wgv);   // h_prev * wg in a-slot
                    h = fmaf(aa, h, bv);
                }
            }
        }
        __syncthreads();
        {
            int t = tid >> 2, q = tid & 3;
            float s = 0.0f;
            #pragma unroll
            for (int j = 0; j < 32; ++j){
                int col = q*32 + j;
                s += bf2f(s_ab[col*H_ + (((t >> 2) ^ (col & 15)) << 3) + (t & 3)*2]);
            }
            s += __shfl_xor(s, 1, 64);
            s += __shfl_xor(s, 2, 64);
            if (q == 0) preds[(size_t)bb*L_ + t0g + t] = s + bg[0];
        }
    }
}

// K3: stage stored ab tile -> LDS, carried scan + fused readout. Memory-bound.
__global__ __launch_bounds__(256, 4)
void scan_readout(const unsigned short* __restrict__ ab_g,
                  const float* __restrict__ carry,
                  const float* __restrict__ Wg, const float* __restrict__ bg,
                  float* __restrict__ preds)
{
    __shared__ __align__(16) unsigned short s_ab[H_*H_];
    __shared__ float s_wg[H_];
    const int bid = blockIdx.x;
    const int bb  = bid / C_;
    const int cc  = bid % C_;
    const int t0g = cc * T_;
    const int tid = threadIdx.x;
    const int wv = tid >> 6, lane = tid & 63;

    {
        const char* src = (const char*)(ab_g + (size_t)bid * (H_*H_));
        char* dst = (char*)s_ab;
        #pragma unroll
        for (int i = 0; i < 8; ++i){
            int off = (wv*8 + i)*1024;
            __builtin_amdgcn_global_load_lds(
                (const __attribute__((address_space(1))) unsigned int*)(src + off + lane*16),
                (__attribute__((address_space(3))) unsigned int*)(dst + off), 16, 0, 0);
        }
    }
    if (tid < H_) s_wg[tid] = Wg[tid];
    __syncthreads();

    if (tid < H_){
        float h = carry[cc*BH_ + bb*H_ + tid];
        float wgv = s_wg[tid];
        #pragma unroll
        for (int t4 = 0; t4 < 16; ++t4){
            int base = tid*H_ + ((t4 ^ (tid & 15)) << 3);
            short8 pr = *(const short8*)&s_ab[base];
            #pragma unroll
            for (int e = 0; e < 4; ++e){
                float aa = bf2f((unsigned short)pr[2*e]);
                float bv = bf2f((unsigned short)pr[2*e+1]);
                s_ab[base + 2*e] = f2bf(h * wgv);
                h = fmaf(aa, h, bv);
            }
        }
    }
    __syncthreads();
    {
        int t = tid >> 2, q = tid & 3;
        float s = 0.0f;
        #pragma unroll
        for (int j = 0; j < 32; ++j){
            int col = q*32 + j;
            s += bf2f(s_ab[col*H_ + (((t >> 2) ^ (col & 15)) << 3) + (t & 3)*2]);
        }
        s += __shfl_xor(s, 1, 64);
        s += __shfl_xor(s, 2, 64);
        if (q == 0) preds[(size_t)bb*L_ + t0g + t] = s + bg[0];
    }
}

extern "C" void kernel_launch(void* const* d_in, const int* in_sizes, int n_in,
                              void* d_out, int out_size, void* d_ws, size_t ws_size,
                              hipStream_t stream){
    const float* x  = (const float*)d_in[0];
    const float* Wp = (const float*)d_in[1];
    const float* bp = (const float*)d_in[2];
    const float* Wz = (const float*)d_in[3];
    const float* bz = (const float*)d_in[4];
    const float* Wh = (const float*)d_in[5];
    const float* bh = (const float*)d_in[6];
    const float* Wg = (const float*)d_in[7];
    const float* bg = (const float*)d_in[8];
    float* preds = (float*)d_out;

    uint8_t* w8 = (uint8_t*)d_ws;
    unsigned short* WzT = (unsigned short*)(w8);
    unsigned short* WhT = (unsigned short*)(w8 + 32768);
    float* aggA  = (float*)(w8 + 65536);
    float* aggB  = (float*)(w8 + 65536 + 4u*BH_*C_);
    float* carry = (float*)(w8 + 65536 + 8u*BH_*C_);
    unsigned short* ab_g = (unsigned short*)(w8 + 65536 + 12u*BH_*C_);

    const size_t need = 65536 + 12u*BH_*C_ + (size_t)B_*C_*(H_*H_)*2u;  // ~140.6 MB
    const bool store_ab = ws_size >= need;

    hipLaunchKernelGGL(prep_w, dim3(2), dim3(256), 0, stream, Wz, Wh, WzT, WhT);
    if (store_ab){
        hipLaunchKernelGGL(HIP_KERNEL_NAME(gemm_gates<true,false>), dim3(B_*C_), dim3(256), 0, stream,
                           x, Wp, bp, bz, bh, Wg, bg, WzT, WhT,
                           aggA, aggB, (const float*)nullptr, ab_g, (float*)nullptr);
        hipLaunchKernelGGL(chunk_scan, dim3(BH_/256), dim3(256), 0, stream, aggA, aggB, carry);
        hipLaunchKernelGGL(scan_readout, dim3(B_*C_), dim3(256), 0, stream,
                           ab_g, carry, Wg, bg, preds);
    } else {
        hipLaunchKernelGGL(HIP_KERNEL_NAME(gemm_gates<false,false>), dim3(B_*C_), dim3(256), 0, stream,
                           x, Wp, bp, bz, bh, Wg, bg, WzT, WhT,
                           aggA, aggB, (const float*)nullptr, (unsigned short*)nullptr, (float*)nullptr);
        hipLaunchKernelGGL(chunk_scan, dim3(BH_/256), dim3(256), 0, stream, aggA, aggB, carry);
        hipLaunchKernelGGL(HIP_KERNEL_NAME(gemm_gates<false,true>), dim3(B_*C_), dim3(256), 0, stream,
                           x, Wp, bp, bz, bh, Wg, bg, WzT, WhT,
                           (float*)nullptr, (float*)nullptr, carry, (unsigned short*)nullptr, preds);
    }
}